// Round 10
// baseline (556.096 us; speedup 1.0000x reference)
//
#include <hip/hip_runtime.h>
#include <hip/hip_bf16.h>
#include <stdint.h>

// GATv2: A=128, S=64, P=16, F=128, H=4, D=128.
// Inputs f32; OUTPUTS f32. MFMA bf16.
// R5 (7th submission; six infra failures, never yet benched): tail elimination.
//     R4 showed time-avg occupancy 50.2% == (3+1)/2 blocks: 3-block residency vs
//     4 blocks/CU of work -> half the wall clock at 1 block/CU.
//  - d-half split: Gs[64][136] (17.4 KB), LDS ~25.9 KB -> 4 blocks/CU (thread-capped).
//  - half is OUTER loop: acc[4] (16 regs) live, epilogue per half -> total regs <=64
//    so 32 waves/CU fit. A-frags + P rebuilt per (half,head) (L3-hot / VALU headroom).
//  - grid 1024 == 4 blocks/CU * 256 CU: single full round, no tail.
//  - FP order per output element unchanged -> bit-identical to R4 output.

typedef short short8 __attribute__((ext_vector_type(8)));
typedef float f32x4 __attribute__((ext_vector_type(4)));

__device__ __forceinline__ float bf2f(unsigned short u) {
    return __uint_as_float(((unsigned int)u) << 16);
}
__device__ __forceinline__ unsigned short f2bf(float f) {
    unsigned int x = __float_as_uint(f);
    return (unsigned short)((x + 0x7FFFu + ((x >> 16) & 1u)) >> 16);
}
__device__ __forceinline__ float lrelu(float x) {
    return fmaxf(x, 0.2f * x);   // slope in (0,1): max(x,0.2x) == leaky_relu, monotone
}

// Precompute: Wt[hd][f] = bf16(W_r[f][hd])  (B-operand, W^T)
//             V_l[h][f] = sum_d W_l[f][h*128+d] * w_attn[d]      (f32 exact)
//             V_r[h][f] = sum_d W_r[f][h*128+d] * w_attn[128+d]  (f32 exact)
__global__ void gat_precomp(const float* __restrict__ Wl,
                            const float* __restrict__ Wr,
                            const float* __restrict__ wattn,
                            unsigned short* __restrict__ Wt,
                            float* __restrict__ Vl,
                            float* __restrict__ Vr) {
    int b = blockIdx.x, t = threadIdx.x;
    if (b < 64) {
        int base = b * 1024 + t * 4;          // linear index into W_r (F x 512)
        float4 v = *(const float4*)(Wr + base);
        int f = base >> 9;
        int c = base & 511;                   // hd
        Wt[(c + 0) * 128 + f] = f2bf(v.x);
        Wt[(c + 1) * 128 + f] = f2bf(v.y);
        Wt[(c + 2) * 128 + f] = f2bf(v.z);
        Wt[(c + 3) * 128 + f] = f2bf(v.w);
    } else {
        const float* W  = (b == 64) ? Wl : Wr;
        const float* aw = wattn + ((b == 64) ? 0 : 128);
        float* V = (b == 64) ? Vl : Vr;
        for (int r = 0; r < 2; ++r) {
            int o = t + r * 256;
            int f = o >> 2, hh = o & 3;
            float acc = 0.f;
            #pragma unroll 4
            for (int d = 0; d < 128; d += 4) {
                float4 wv = *(const float4*)(W + f * 512 + hh * 128 + d);
                float4 av = *(const float4*)(aw + d);
                acc += wv.x * av.x + wv.y * av.y + wv.z * av.z + wv.w * av.w;
            }
            V[hh * 128 + f] = acc;
        }
    }
}

// One block per (s,p). 512 threads = 8 waves; wave w owns a 16-row strip.
__global__ __launch_bounds__(512, 8)
void gat_main(const float* __restrict__ hin,
              const unsigned short* __restrict__ Wt,
              const float* __restrict__ Vl,
              const float* __restrict__ Vr,
              float* __restrict__ out_attn,
              float* __restrict__ out_a) {
    __shared__ __align__(16) unsigned short Gs[64][136];   // G_hi half, transposed [d][j]
    __shared__ __align__(16) float sLs[4][132];
    __shared__ __align__(16) float sRs[4][132];
    __shared__ __align__(16) float Ms[4][132];
    __shared__ __align__(16) float Siv[4][132];
    __shared__ float mx1[4], mx2[4];
    __shared__ int   ax1[4];

    const int sp = blockIdx.x;                // sp = s*16 + p
    const int t = threadIdx.x;
    const int w = t >> 6;                     // wave id 0..7
    const int l = t & 63;
    const int q = l >> 4;                     // quad 0..3
    const int ln = l & 15;

    // ---- A. s_l[a][h] = h_row . V_l[h], s_r likewise — f32 exact from global
    {
        int a = t >> 2, hh = t & 3;
        const float* hr = hin + (size_t)a * 131072 + sp * 128;
        const float* vl = Vl + hh * 128;
        const float* vr = Vr + hh * 128;
        float al = 0.f, ar = 0.f;
        for (int f = 0; f < 128; f += 4) {
            float4 x  = *(const float4*)(hr + f);
            float4 a4 = *(const float4*)(vl + f);
            float4 b4 = *(const float4*)(vr + f);
            al += x.x * a4.x + x.y * a4.y + x.z * a4.z + x.w * a4.w;
            ar += x.x * b4.x + x.y * b4.y + x.z * b4.z + x.w * b4.w;
        }
        sLs[hh][a] = al;
        sRs[hh][a] = ar;
    }
    __syncthreads();

    // ---- B. per-head top-2 (value,argmax) of s_l — replaces the 128-iter max pass.
    // Exact: lrelu monotone => max_{j!=i} lrelu(sR+sL[j]) = lrelu(sR + max_{j!=i} sL[j]).
    if (w < 4) {
        float v0 = sLs[w][l], v1 = sLs[w][l + 64];
        float m1, m2; int a1;
        if (v0 >= v1) { m1 = v0; m2 = v1; a1 = l; }
        else          { m1 = v1; m2 = v0; a1 = l + 64; }
        #pragma unroll
        for (int off = 32; off; off >>= 1) {
            float o1 = __shfl_down(m1, off);
            float o2 = __shfl_down(m2, off);
            int   ob = __shfl_down(a1, off);
            if (o1 > m1) { m2 = fmaxf(m1, o2); m1 = o1; a1 = ob; }
            else         { m2 = fmaxf(m2, o1); }
        }
        if (l == 0) { mx1[w] = m1; mx2[w] = m2; ax1[w] = a1; }
    }
    __syncthreads();

    // ---- C. per-(i,h): m from top-2, then sum pass (diag removed by subtraction)
    {
        int i = t >> 2, hh = t & 3;
        float sr = sRs[hh][i];
        float Mi = (i == ax1[hh]) ? mx2[hh] : mx1[hh];
        float m = lrelu(sr + Mi);
        float sum = 0.f;
        for (int j4 = 0; j4 < 128; j4 += 4) {
            float4 sl4 = *(const float4*)(&sLs[hh][j4]);
            sum += __expf(lrelu(sr + sl4.x) - m);
            sum += __expf(lrelu(sr + sl4.y) - m);
            sum += __expf(lrelu(sr + sl4.z) - m);
            sum += __expf(lrelu(sr + sl4.w) - m);
        }
        sum -= __expf(lrelu(sr + sLs[hh][i]) - m);   // remove diagonal term
        Ms[hh][i] = m;
        Siv[hh][i] = 1.f / sum;
    }
    __syncthreads();

    // ---- D. write attention weights a[s,p,i,j,h] as f32 (float4, coalesced)
    {
        float* oa = out_a + (size_t)sp * 65536;
        for (int k = 0; k < 32; ++k) {
            int idx = k * 512 + t;
            int i = idx >> 7, j = idx & 127;
            float4 r4;
            float* rp = (float*)&r4;
            #pragma unroll
            for (int hh = 0; hh < 4; ++hh) {
                float pv = 0.f;
                if (j != i) {
                    float e = lrelu(sRs[hh][i] + sLs[hh][j]);
                    pv = __expf(e - Ms[hh][i]) * Siv[hh][i];
                }
                rp[hh] = pv;
            }
            *(float4*)(oa + (size_t)idx * 4) = r4;
        }
    }

    // ---- E. half-outer head loop: per (half,hh): G half = X @ W (bf16-hi),
    //          attn_half += P_h @ G_half. acc only 4 f32x4 live.
    const float* hrw = hin + (size_t)(16 * w + ln) * 131072 + sp * 128;
    const int irow = 16 * w + ln;

    for (int half = 0; half < 2; ++half) {
        f32x4 acc4[4];
        #pragma unroll
        for (int tjh = 0; tjh < 4; ++tjh) acc4[tjh] = (f32x4){0.f, 0.f, 0.f, 0.f};

        for (int hh = 0; hh < 4; ++hh) {
            __syncthreads();  // previous PV/epilogue reads of Gs complete

            // A-fragments of X rows (bf16 hi), rebuilt per (half,hh): L2/L3-hot,
            // keeps register peak low for 8 waves/SIMD.
            short8 axh[4];
            #pragma unroll
            for (int kb = 0; kb < 4; ++kb) {
                float4 xa = *(const float4*)(hrw + 32 * kb + 8 * q);
                float4 xb = *(const float4*)(hrw + 32 * kb + 8 * q + 4);
                short8 v;
                v[0] = (short)f2bf(xa.x); v[1] = (short)f2bf(xa.y);
                v[2] = (short)f2bf(xa.z); v[3] = (short)f2bf(xa.w);
                v[4] = (short)f2bf(xb.x); v[5] = (short)f2bf(xb.y);
                v[6] = (short)f2bf(xb.z); v[7] = (short)f2bf(xb.w);
                axh[kb] = v;
            }

            #pragma unroll
            for (int tjh = 0; tjh < 4; ++tjh) {
                f32x4 g = (f32x4){0.f, 0.f, 0.f, 0.f};
                #pragma unroll
                for (int kb = 0; kb < 4; ++kb) {
                    // B-frag: Wt[hd = hh*128 + 64*half + 16*tjh + ln][f] (L2-hot)
                    short8 bh = *(const short8*)(Wt + ((hh * 128 + 64 * half + 16 * tjh + ln) * 128 + 32 * kb + 8 * q));
                    g = __builtin_amdgcn_mfma_f32_16x16x32_bf16(axh[kb], bh, g, 0, 0, 0);
                }
                // C layout: row a = 16w+4q+r, col d -> store G^T hi: Gs[dlocal][a].
                ushort4 gh4;
                unsigned short* ghp = (unsigned short*)&gh4;
                #pragma unroll
                for (int r = 0; r < 4; ++r) ghp[r] = f2bf(g[r]);
                *(ushort4*)(&Gs[16 * tjh + ln][16 * w + 4 * q]) = gh4;
            }
            __syncthreads();

            // PV: kb-outer, one P hi/lo pair live; 2 MFMA per (kb,tjh).
            {
                const float sr = sRs[hh][irow];
                const float m = Ms[hh][irow];
                const float si = Siv[hh][irow];
                #pragma unroll 1
                for (int kb = 0; kb < 4; ++kb) {
                    short8 ph, pl;
                    #pragma unroll
                    for (int jj = 0; jj < 8; ++jj) {
                        int j = 32 * kb + 8 * q + jj;
                        float pv = 0.f;
                        if (j != irow) {
                            float e = lrelu(sr + sLs[hh][j]);
                            pv = __expf(e - m) * si;
                        }
                        unsigned short hb = f2bf(pv);
                        ph[jj] = (short)hb;
                        pl[jj] = (short)f2bf(pv - bf2f(hb));
                    }
                    #pragma unroll
                    for (int tjh = 0; tjh < 4; ++tjh) {
                        short8 bh = *(const short8*)(&Gs[16 * tjh + ln][32 * kb + 8 * q]);
                        acc4[tjh] = __builtin_amdgcn_mfma_f32_16x16x32_bf16(ph, bh, acc4[tjh], 0, 0, 0);
                        acc4[tjh] = __builtin_amdgcn_mfma_f32_16x16x32_bf16(pl, bh, acc4[tjh], 0, 0, 0);
                    }
                }
            }
        }

        // ---- F. epilogue for this half: attn_res[a][sp][d] = 0.25 * acc, f32
        #pragma unroll
        for (int tjh = 0; tjh < 4; ++tjh) {
            int d = 64 * half + 16 * tjh + ln;
            #pragma unroll
            for (int r = 0; r < 4; ++r) {
                int i = 16 * w + 4 * q + r;
                out_attn[((size_t)i * 1024 + sp) * 128 + d] = acc4[tjh][r] * 0.25f;
            }
        }
    }
}

extern "C" void kernel_launch(void* const* d_in, const int* in_sizes, int n_in,
                              void* d_out, int out_size, void* d_ws, size_t ws_size,
                              hipStream_t stream) {
    const float* hin   = (const float*)d_in[0];
    const float* Wl    = (const float*)d_in[1];
    const float* Wr    = (const float*)d_in[2];
    const float* wattn = (const float*)d_in[3];

    unsigned short* Wt = (unsigned short*)d_ws;                    // 65536 bf16 = 128 KiB
    float* Vl = (float*)((char*)d_ws + 131072);                    // 512 f32
    float* Vr = (float*)((char*)d_ws + 131072 + 2048);             // 512 f32

    float* out_attn = (float*)d_out;                               // 16,777,216 f32
    float* out_a    = (float*)d_out + 16777216;                    // 67,108,864 f32

    gat_precomp<<<66, 256, 0, stream>>>(Wl, Wr, wattn, Wt, Vl, Vr);
    gat_main<<<1024, 512, 0, stream>>>(hin, Wt, Vl, Vr, out_attn, out_a);
}